// Round 7
// baseline (210.981 us; speedup 1.0000x reference)
//
#include <hip/hip_runtime.h>
#include <math.h>

#define NBLK 784
#define O_ 32
#define N_ 144
#define D_ 16
#define PS 20    // padded LDS row stride for P (floats)
#define RS 148   // padded LDS row stride for R (floats)

#define STATS_STRIDE 36                 // mu[16], isg[16], LC @32 (pad to 36)
#define WS_STATS_FLOATS (25088 * STATS_STRIDE)
#define WS_R_FLOATS     (784 * 32 * 144)
#define WS_NEED_BYTES   ((size_t)(WS_STATS_FLOATS + WS_R_FLOATS) * 4)

// ======================= multi-kernel path =======================

// moments kernel: per (pixel, o-octet). 128 thr = 8 o x 16 lanes, 9 n each.
// rmode 0: r = acts/32 (iter 0). rmode 1: r = R[pix][o][n] (pre-multiplied by A).
// fin 0: write stats (mu,isg,LC). fin 1: write outputs (mu, a_out).
__global__ __launch_bounds__(128) void caps_mom(
    const float* __restrict__ poses,
    const float* __restrict__ acts,
    const float* __restrict__ kern,
    const float* __restrict__ Rw,
    const float* __restrict__ beta_a,
    const float* __restrict__ beta_u,
    float* __restrict__ stats,
    float* __restrict__ out,
    int rmode, int fin, float invtemp)
{
    const int pix = blockIdx.x;
    const int b  = pix / 196;
    const int hw = pix - b * 196;
    const int ho = hw / 14;
    const int wo = hw - ho * 14;

    const int t  = threadIdx.x;
    const int o  = blockIdx.y * 8 + (t >> 4);
    const int s  = t & 15;

    const float* Kbase = kern + (size_t)o * (N_ * D_);
    const float* Rrow  = Rw + ((size_t)pix * 32 + o) * 144;

    float S1[16], S2[16];
#pragma unroll
    for (int d = 0; d < 16; ++d) { S1[d] = 0.f; S2[d] = 0.f; }
    float rs = 0.f;

#pragma unroll
    for (int k = 0; k < 9; ++k) {
        const int n = s + (k << 4);
        const int ki = n / 48, kj = (n >> 4) - (n / 48) * 3, c = n & 15;
        const int cell = (b * 16 + ho + ki) * 16 + (wo + kj);
        float r;
        if (rmode) r = Rrow[n];
        else       r = acts[cell * 16 + c] * 0.03125f;
        rs += r;
        float pv[16], kv[16];
        const float4* Pp = (const float4*)(poses + (size_t)cell * 256 + c * 16);
        ((float4*)pv)[0] = Pp[0];
        ((float4*)pv)[1] = Pp[1];
        ((float4*)pv)[2] = Pp[2];
        ((float4*)pv)[3] = Pp[3];
        const float4* Kp = (const float4*)(Kbase + n * D_);
        ((float4*)kv)[0] = Kp[0];
        ((float4*)kv)[1] = Kp[1];
        ((float4*)kv)[2] = Kp[2];
        ((float4*)kv)[3] = Kp[3];
#pragma unroll
        for (int i = 0; i < 4; ++i) {
#pragma unroll
            for (int l = 0; l < 4; ++l) {
                float v = fmaf(pv[i*4+0], kv[0+l],
                          fmaf(pv[i*4+1], kv[4+l],
                          fmaf(pv[i*4+2], kv[8+l],
                               pv[i*4+3] * kv[12+l])));
                S1[i*4+l] = fmaf(r, v, S1[i*4+l]);
                S2[i*4+l] = fmaf(r * v, v, S2[i*4+l]);
            }
        }
    }

    // butterfly over the 16 lanes sharing this o (within wave)
#pragma unroll
    for (int m = 1; m < 16; m <<= 1) {
        rs += __shfl_xor(rs, m, 64);
#pragma unroll
        for (int d = 0; d < 16; ++d) {
            S1[d] += __shfl_xor(S1[d], m, 64);
            S2[d] += __shfl_xor(S2[d], m, 64);
        }
    }

    rs += 1e-9f;
    const float inv_rs = 1.0f / rs;
    float mu[16], sig[16];
#pragma unroll
    for (int d = 0; d < 16; ++d) {
        mu[d] = S1[d] * inv_rs;
        sig[d] = fmaf(-mu[d], mu[d], S2[d] * inv_rs) + 1e-9f;
    }
    const float L = __logf(sig[0]  * sig[1])  + __logf(sig[2]  * sig[3])
                  + __logf(sig[4]  * sig[5])  + __logf(sig[6]  * sig[7])
                  + __logf(sig[8]  * sig[9])  + __logf(sig[10] * sig[11])
                  + __logf(sig[12] * sig[13]) + __logf(sig[14] * sig[15]);
    const float cost = rs * fmaf(0.5f, L, 16.0f * beta_u[o]);
    const float x = invtemp * (beta_a[o] - cost);
    const float a_out = 1.0f / (1.0f + __expf(-x));

    if (s == 0) {
        if (fin) {
            float4* ob = (float4*)(out + (size_t)pix * 512 + o * 16);
            ob[0] = make_float4(mu[0],  mu[1],  mu[2],  mu[3]);
            ob[1] = make_float4(mu[4],  mu[5],  mu[6],  mu[7]);
            ob[2] = make_float4(mu[8],  mu[9],  mu[10], mu[11]);
            ob[3] = make_float4(mu[12], mu[13], mu[14], mu[15]);
            out[401408 + pix * 32 + o] = a_out;
        } else {
            float* sb = stats + ((size_t)pix * 32 + o) * STATS_STRIDE;
            float4* sb4 = (float4*)sb;
            sb4[0] = make_float4(mu[0],  mu[1],  mu[2],  mu[3]);
            sb4[1] = make_float4(mu[4],  mu[5],  mu[6],  mu[7]);
            sb4[2] = make_float4(mu[8],  mu[9],  mu[10], mu[11]);
            sb4[3] = make_float4(mu[12], mu[13], mu[14], mu[15]);
            float isg[16];
#pragma unroll
            for (int d = 0; d < 16; ++d) isg[d] = 1.0f / sig[d];
            sb4[4] = make_float4(isg[0],  isg[1],  isg[2],  isg[3]);
            sb4[5] = make_float4(isg[4],  isg[5],  isg[6],  isg[7]);
            sb4[6] = make_float4(isg[8],  isg[9],  isg[10], isg[11]);
            sb4[7] = make_float4(isg[12], isg[13], isg[14], isg[15]);
            sb[32] = __logf(a_out + 1e-9f)
                   - 0.5f * (16.0f * 1.8378770664093453f + L);
        }
    }
}

// logits+softmax kernel: per (pixel, 24-n slab). 256 thr = 32 o x 8 lanes, 3 n each.
// writes R[pix][o][n] = softmax_o(logits) * A[n]
__global__ __launch_bounds__(256) void caps_logits(
    const float* __restrict__ poses,
    const float* __restrict__ acts,
    const float* __restrict__ kern,
    const float* __restrict__ stats,
    float* __restrict__ Rw)
{
    const int pix  = blockIdx.x;
    const int slab = blockIdx.y;           // 0..5, 24 n each
    const int b  = pix / 196;
    const int hw = pix - b * 196;
    const int ho = hw / 14;
    const int wo = hw - ho * 14;

    const int t  = threadIdx.x;
    const int o  = t >> 3;
    const int ln = t & 7;

    __shared__ float Lg[24][33];
    __shared__ float Al[24];
    __shared__ float Rl[32][24];

    if (t < 24) {
        const int n = slab * 24 + t;
        const int ki = n / 48, kj = (n >> 4) - (n / 48) * 3, c = n & 15;
        Al[t] = acts[((b * 16 + ho + ki) * 16 + (wo + kj)) * 16 + c];
    }

    // per-o stats into registers
    float mu[16], isg[16];
    const float* sb = stats + ((size_t)pix * 32 + o) * STATS_STRIDE;
    const float4* sb4 = (const float4*)sb;
    ((float4*)mu)[0]  = sb4[0]; ((float4*)mu)[1]  = sb4[1];
    ((float4*)mu)[2]  = sb4[2]; ((float4*)mu)[3]  = sb4[3];
    ((float4*)isg)[0] = sb4[4]; ((float4*)isg)[1] = sb4[5];
    ((float4*)isg)[2] = sb4[6]; ((float4*)isg)[3] = sb4[7];
    const float LC = sb[32];

    const float* Kbase = kern + (size_t)o * (N_ * D_);

#pragma unroll
    for (int j = 0; j < 3; ++j) {
        const int nl = ln * 3 + j;
        const int n  = slab * 24 + nl;
        const int ki = n / 48, kj = (n >> 4) - (n / 48) * 3, c = n & 15;
        const int cell = (b * 16 + ho + ki) * 16 + (wo + kj);
        float pv[16], kv[16];
        const float4* Pp = (const float4*)(poses + (size_t)cell * 256 + c * 16);
        ((float4*)pv)[0] = Pp[0];
        ((float4*)pv)[1] = Pp[1];
        ((float4*)pv)[2] = Pp[2];
        ((float4*)pv)[3] = Pp[3];
        const float4* Kp = (const float4*)(Kbase + n * D_);
        ((float4*)kv)[0] = Kp[0];
        ((float4*)kv)[1] = Kp[1];
        ((float4*)kv)[2] = Kp[2];
        ((float4*)kv)[3] = Kp[3];
        float Q = 0.f;
#pragma unroll
        for (int i = 0; i < 4; ++i) {
#pragma unroll
            for (int l = 0; l < 4; ++l) {
                float v = fmaf(pv[i*4+0], kv[0+l],
                          fmaf(pv[i*4+1], kv[4+l],
                          fmaf(pv[i*4+2], kv[8+l],
                               pv[i*4+3] * kv[12+l])));
                const float df = v - mu[i*4+l];
                Q = fmaf(df * df, isg[i*4+l], Q);
            }
        }
        Lg[nl][o] = fmaf(-0.5f, Q, LC);
    }
    __syncthreads();

    if (t < 24) {
        float mx = -1e30f;
#pragma unroll
        for (int oo = 0; oo < 32; ++oo) mx = fmaxf(mx, Lg[t][oo]);
        float sm = 0.f;
        float ev[32];
#pragma unroll
        for (int oo = 0; oo < 32; ++oo) {
            ev[oo] = __expf(Lg[t][oo] - mx);
            sm += ev[oo];
        }
        const float sc = Al[t] / sm;
#pragma unroll
        for (int oo = 0; oo < 32; ++oo) Rl[oo][t] = ev[oo] * sc;
    }
    __syncthreads();

    // coalesced store of R
#pragma unroll
    for (int rep = 0; rep < 3; ++rep) {
        const int idx = t + rep * 256;
        const int oo = idx / 24;
        const int nl = idx - oo * 24;
        Rw[((size_t)pix * 32 + oo) * 144 + slab * 24 + nl] = Rl[oo][nl];
    }
}

// ======================= fallback: R6 single kernel =======================

__global__ __launch_bounds__(256) void convcaps_em(
    const float* __restrict__ poses,
    const float* __restrict__ acts,
    const float* __restrict__ kern,
    const float* __restrict__ beta_a,
    const float* __restrict__ beta_u,
    float* __restrict__ out)
{
    const int pix = blockIdx.x;
    const int b  = pix / 196;
    const int hw = pix - b * 196;
    const int ho = hw / 14;
    const int wo = hw - ho * 14;

    __shared__ __align__(16) float P[N_ * PS];
    __shared__ float A[N_];
    __shared__ float Rm[O_ * RS];

    const int t = threadIdx.x;

    for (int idx = t; idx < N_ * D_; idx += 256) {
        int n = idx >> 4, d = idx & 15;
        int ki = n / 48, kj = (n >> 4) - ki * 3, c = n & 15;
        P[n * PS + d] = poses[((b * 16 + ho + ki) * 16 + (wo + kj)) * 256 + c * 16 + d];
    }
    if (t < N_) {
        int n = t;
        int ki = n / 48, kj = (n >> 4) - ki * 3, c = n & 15;
        A[n] = acts[((b * 16 + ho + ki) * 16 + (wo + kj)) * 16 + c];
    }
    __syncthreads();
    for (int idx = t; idx < O_ * N_; idx += 256) {
        int oo = idx / N_;
        int nn = idx - oo * N_;
        Rm[oo * RS + nn] = 0.03125f * A[nn];
    }
    __syncthreads();

    const int o = t >> 3;
    const int s = t & 7;
    const float buv = beta_u[o];
    const float ba  = beta_a[o];
    const float* Kbase = kern + (size_t)o * (N_ * D_);

    float a_out = 0.f;
    float mu[16];

    for (int it = 0; it < 3; ++it) {
        float S1[16], S2[16];
#pragma unroll
        for (int d = 0; d < 16; ++d) { S1[d] = 0.f; S2[d] = 0.f; }
        float rs = 0.f;

#pragma unroll 2
        for (int k = 0; k < 18; ++k) {
            const int n = s + (k << 3);
            const float r = Rm[o * RS + n];
            rs += r;
            float pv[16], kv[16];
            const float4* Pp = (const float4*)(P + n * PS);
            ((float4*)pv)[0] = Pp[0];
            ((float4*)pv)[1] = Pp[1];
            ((float4*)pv)[2] = Pp[2];
            ((float4*)pv)[3] = Pp[3];
            const float4* Kp = (const float4*)(Kbase + n * D_);
            ((float4*)kv)[0] = Kp[0];
            ((float4*)kv)[1] = Kp[1];
            ((float4*)kv)[2] = Kp[2];
            ((float4*)kv)[3] = Kp[3];
#pragma unroll
            for (int i = 0; i < 4; ++i) {
#pragma unroll
                for (int l = 0; l < 4; ++l) {
                    float v = fmaf(pv[i*4+0], kv[0+l],
                              fmaf(pv[i*4+1], kv[4+l],
                              fmaf(pv[i*4+2], kv[8+l],
                                   pv[i*4+3] * kv[12+l])));
                    S1[i*4+l] = fmaf(r, v, S1[i*4+l]);
                    S2[i*4+l] = fmaf(r * v, v, S2[i*4+l]);
                }
            }
        }

#pragma unroll
        for (int m = 1; m < 8; m <<= 1) {
            rs += __shfl_xor(rs, m, 64);
#pragma unroll
            for (int d = 0; d < 16; ++d) {
                S1[d] += __shfl_xor(S1[d], m, 64);
                S2[d] += __shfl_xor(S2[d], m, 64);
            }
        }

        rs += 1e-9f;
        const float inv_rs = 1.0f / rs;
        float sig[16];
#pragma unroll
        for (int d = 0; d < 16; ++d) {
            mu[d] = S1[d] * inv_rs;
            sig[d] = fmaf(-mu[d], mu[d], S2[d] * inv_rs) + 1e-9f;
        }
        const float L = __logf(sig[0]  * sig[1])  + __logf(sig[2]  * sig[3])
                      + __logf(sig[4]  * sig[5])  + __logf(sig[6]  * sig[7])
                      + __logf(sig[8]  * sig[9])  + __logf(sig[10] * sig[11])
                      + __logf(sig[12] * sig[13]) + __logf(sig[14] * sig[15]);
        const float cost = rs * fmaf(0.5f, L, 16.0f * buv);
        const float x = (float)(it + 1) * (ba - cost);
        a_out = 1.0f / (1.0f + __expf(-x));

        if (it < 2) {
            float isg[16];
#pragma unroll
            for (int d = 0; d < 16; ++d) isg[d] = 1.0f / sig[d];
            const float LC = __logf(a_out + 1e-9f)
                           - 0.5f * (16.0f * 1.8378770664093453f + L);
            __syncthreads();

#pragma unroll 2
            for (int k = 0; k < 18; ++k) {
                const int n = s + (k << 3);
                float pv[16], kv[16];
                const float4* Pp = (const float4*)(P + n * PS);
                ((float4*)pv)[0] = Pp[0];
                ((float4*)pv)[1] = Pp[1];
                ((float4*)pv)[2] = Pp[2];
                ((float4*)pv)[3] = Pp[3];
                const float4* Kp = (const float4*)(Kbase + n * D_);
                ((float4*)kv)[0] = Kp[0];
                ((float4*)kv)[1] = Kp[1];
                ((float4*)kv)[2] = Kp[2];
                ((float4*)kv)[3] = Kp[3];
                float Q = 0.f;
#pragma unroll
                for (int i = 0; i < 4; ++i) {
#pragma unroll
                    for (int l = 0; l < 4; ++l) {
                        float v = fmaf(pv[i*4+0], kv[0+l],
                                  fmaf(pv[i*4+1], kv[4+l],
                                  fmaf(pv[i*4+2], kv[8+l],
                                       pv[i*4+3] * kv[12+l])));
                        const float df = v - mu[i*4+l];
                        Q = fmaf(df * df, isg[i*4+l], Q);
                    }
                }
                Rm[o * RS + n] = fmaf(-0.5f, Q, LC);
            }
            __syncthreads();

            if (t < N_) {
                float v[32];
                float mx = -1e30f;
#pragma unroll
                for (int oo = 0; oo < 32; ++oo) {
                    v[oo] = Rm[oo * RS + t];
                    mx = fmaxf(mx, v[oo]);
                }
                float sm = 0.f;
#pragma unroll
                for (int oo = 0; oo < 32; ++oo) {
                    v[oo] = __expf(v[oo] - mx);
                    sm += v[oo];
                }
                const float sc = A[t] / sm;
#pragma unroll
                for (int oo = 0; oo < 32; ++oo)
                    Rm[oo * RS + t] = v[oo] * sc;
            }
            __syncthreads();
        }
    }

    if (s == 0) {
        float4* ob = (float4*)(out + (size_t)pix * 512 + o * 16);
        ob[0] = make_float4(mu[0],  mu[1],  mu[2],  mu[3]);
        ob[1] = make_float4(mu[4],  mu[5],  mu[6],  mu[7]);
        ob[2] = make_float4(mu[8],  mu[9],  mu[10], mu[11]);
        ob[3] = make_float4(mu[12], mu[13], mu[14], mu[15]);
        out[401408 + pix * 32 + o] = a_out;
    }
}

extern "C" void kernel_launch(void* const* d_in, const int* in_sizes, int n_in,
                              void* d_out, int out_size, void* d_ws, size_t ws_size,
                              hipStream_t stream)
{
    const float* poses  = (const float*)d_in[0];
    const float* acts   = (const float*)d_in[1];
    const float* kern   = (const float*)d_in[2];
    const float* beta_a = (const float*)d_in[3];
    const float* beta_u = (const float*)d_in[4];
    float* out = (float*)d_out;

    if (ws_size >= WS_NEED_BYTES) {
        float* stats = (float*)d_ws;
        float* Rw    = stats + WS_STATS_FLOATS;
        dim3 gm(NBLK, 4), gl(NBLK, 6);
        caps_mom<<<gm, 128, 0, stream>>>(poses, acts, kern, Rw, beta_a, beta_u,
                                         stats, out, 0, 0, 1.0f);
        caps_logits<<<gl, 256, 0, stream>>>(poses, acts, kern, stats, Rw);
        caps_mom<<<gm, 128, 0, stream>>>(poses, acts, kern, Rw, beta_a, beta_u,
                                         stats, out, 1, 0, 2.0f);
        caps_logits<<<gl, 256, 0, stream>>>(poses, acts, kern, stats, Rw);
        caps_mom<<<gm, 128, 0, stream>>>(poses, acts, kern, Rw, beta_a, beta_u,
                                         stats, out, 1, 1, 3.0f);
    } else {
        convcaps_em<<<NBLK, 256, 0, stream>>>(poses, acts, kern, beta_a, beta_u, out);
    }
}

// Round 8
// 104.140 us; speedup vs baseline: 2.0259x; 2.0259x over previous
//
#include <hip/hip_runtime.h>
#include <math.h>

#define NBLK 784
#define O_ 32
#define N_ 144
#define D_ 16
#define PS 20    // padded LDS row stride for P (floats); 80B rows, float4-aligned
#define RS 148   // padded LDS row stride for R (floats)

// DPP-based 8-lane allreduce (lanes grouped s = t&7, aligned to DPP rows).
// quad_perm[1,0,3,2]=0xB1 (xor1), quad_perm[2,3,0,1]=0x4E (xor2),
// row_half_mirror=0x141 (pairs quads within each 8-lane half-row).
#define DPPADD(x, ctrl) ((x) + __int_as_float(                                 \
    __builtin_amdgcn_update_dpp(0, __float_as_int(x), ctrl, 0xF, 0xF, true)))

__device__ __forceinline__ float sum8(float x) {
    x = DPPADD(x, 0xB1);
    x = DPPADD(x, 0x4E);
    x = DPPADD(x, 0x141);
    return x;
}

__global__ __launch_bounds__(256) void convcaps_em(
    const float* __restrict__ poses,
    const float* __restrict__ acts,
    const float* __restrict__ kern,
    const float* __restrict__ beta_a,
    const float* __restrict__ beta_u,
    float* __restrict__ out)
{
    const int pix = blockIdx.x;          // b*196 + ho*14 + wo
    const int b  = pix / 196;
    const int hw = pix - b * 196;
    const int ho = hw / 14;
    const int wo = hw - ho * 14;

    __shared__ __align__(16) float P[N_ * PS];   // pose blocks [n][d]
    __shared__ float A[N_];                      // a_in
    __shared__ float Rm[O_ * RS];                // R*a / logits [o][n]

    const int t = threadIdx.x;

    // ---- load pose block: P[n][d] = poses[b, ho+ki, wo+kj, c, d], n=(ki*3+kj)*16+c
    for (int idx = t; idx < N_ * D_; idx += 256) {
        int n = idx >> 4, d = idx & 15;
        int ki = n / 48, kj = (n >> 4) - ki * 3, c = n & 15;
        P[n * PS + d] = poses[((b * 16 + ho + ki) * 16 + (wo + kj)) * 256 + c * 16 + d];
    }
    if (t < N_) {
        int n = t;
        int ki = n / 48, kj = (n >> 4) - ki * 3, c = n & 15;
        A[n] = acts[((b * 16 + ho + ki) * 16 + (wo + kj)) * 16 + c];
    }
    __syncthreads();
    // ---- init R*a = A[n]/32  (R uniform 1/O; A premultiplied)
    for (int idx = t; idx < O_ * N_; idx += 256) {
        int oo = idx / N_;
        int nn = idx - oo * N_;
        Rm[oo * RS + nn] = 0.03125f * A[nn];
    }
    __syncthreads();

    const int o = t >> 3;                        // 32 capsules
    const int s = t & 7;                         // 8 lanes per capsule, n-slice
    const float buv = beta_u[o];
    const float ba  = beta_a[o];
    const float* Kbase = kern + (size_t)o * (N_ * D_);

    float a_out = 0.f;
    float mu[16];

    for (int it = 0; it < 3; ++it) {
        // ===== pass 1: S1 = Σ rV, S2 = Σ rV², rs = Σ r  (r = R*a from Rm) =====
        float S1[16], S2[16];
#pragma unroll
        for (int d = 0; d < 16; ++d) { S1[d] = 0.f; S2[d] = 0.f; }
        float rs = 0.f;

#pragma unroll 3
        for (int k = 0; k < 18; ++k) {
            const int n = s + (k << 3);
            const float r = Rm[o * RS + n];
            rs += r;
            float pv[16], kv[16];
            const float4* Pp = (const float4*)(P + n * PS);
            ((float4*)pv)[0] = Pp[0];
            ((float4*)pv)[1] = Pp[1];
            ((float4*)pv)[2] = Pp[2];
            ((float4*)pv)[3] = Pp[3];
            const float4* Kp = (const float4*)(Kbase + n * D_);
            ((float4*)kv)[0] = Kp[0];
            ((float4*)kv)[1] = Kp[1];
            ((float4*)kv)[2] = Kp[2];
            ((float4*)kv)[3] = Kp[3];
#pragma unroll
            for (int i = 0; i < 4; ++i) {
#pragma unroll
                for (int l = 0; l < 4; ++l) {
                    // V[i*4+l] = Σ_j P[n][i*4+j] * K[o,n][j*4+l]
                    float v = fmaf(pv[i*4+0], kv[0+l],
                              fmaf(pv[i*4+1], kv[4+l],
                              fmaf(pv[i*4+2], kv[8+l],
                                   pv[i*4+3] * kv[12+l])));
                    S1[i*4+l] = fmaf(r, v, S1[i*4+l]);
                    S2[i*4+l] = fmaf(r * v, v, S2[i*4+l]);
                }
            }
        }

        // allreduce over the 8 lanes sharing this o — DPP (VALU pipe, no DS ops)
        rs = sum8(rs);
#pragma unroll
        for (int d = 0; d < 16; ++d) {
            S1[d] = sum8(S1[d]);
            S2[d] = sum8(S2[d]);
        }

        rs += 1e-9f;                              // r_sum = Σr + EPS
        const float inv_rs = 1.0f / rs;
        float sig[16];
#pragma unroll
        for (int d = 0; d < 16; ++d) {
            mu[d] = S1[d] * inv_rs;
            // sigma2 = E[V²] - mu² + EPS  (== Σ r (V-mu)² / rs + EPS)
            sig[d] = fmaf(-mu[d], mu[d], S2[d] * inv_rs) + 1e-9f;
        }
        // L = Σ_d log(sigma2_d), redundantly per-lane (static idx)
        const float L = __logf(sig[0]  * sig[1])  + __logf(sig[2]  * sig[3])
                      + __logf(sig[4]  * sig[5])  + __logf(sig[6]  * sig[7])
                      + __logf(sig[8]  * sig[9])  + __logf(sig[10] * sig[11])
                      + __logf(sig[12] * sig[13]) + __logf(sig[14] * sig[15]);
        // cost = rs*(D*beta_u + 0.5*L);  a_out = sigmoid(inv_temp*(ba - cost))
        const float cost = rs * fmaf(0.5f, L, 16.0f * buv);
        const float x = (float)(it + 1) * (ba - cost);
        a_out = 1.0f / (1.0f + __expf(-x));

        if (it < 2) {
            // Q = Σ isg·V² - 2Σ isg·mu·V + c0 ; fold c0 into the constant.
            float isg[16], qb[16];
            float c0 = 0.f;
#pragma unroll
            for (int d = 0; d < 16; ++d) {
                isg[d] = 1.0f / sig[d];
                qb[d]  = -2.0f * mu[d] * isg[d];
                c0     = fmaf(mu[d] * mu[d], isg[d], c0);
            }
            // logits = log(a_out+eps) - 0.5*(D*log(2pi) + L) - 0.5*(Qacc + c0)
            const float LC = __logf(a_out + 1e-9f)
                           - 0.5f * (16.0f * 1.8378770664093453f + L)
                           - 0.5f * c0;
            __syncthreads();   // all pass-1 Rm reads done before overwrite

            // ===== pass 2: logits into Rm =====
#pragma unroll 3
            for (int k = 0; k < 18; ++k) {
                const int n = s + (k << 3);
                float pv[16], kv[16];
                const float4* Pp = (const float4*)(P + n * PS);
                ((float4*)pv)[0] = Pp[0];
                ((float4*)pv)[1] = Pp[1];
                ((float4*)pv)[2] = Pp[2];
                ((float4*)pv)[3] = Pp[3];
                const float4* Kp = (const float4*)(Kbase + n * D_);
                ((float4*)kv)[0] = Kp[0];
                ((float4*)kv)[1] = Kp[1];
                ((float4*)kv)[2] = Kp[2];
                ((float4*)kv)[3] = Kp[3];
                float Q = 0.f;
#pragma unroll
                for (int i = 0; i < 4; ++i) {
#pragma unroll
                    for (int l = 0; l < 4; ++l) {
                        float v = fmaf(pv[i*4+0], kv[0+l],
                                  fmaf(pv[i*4+1], kv[4+l],
                                  fmaf(pv[i*4+2], kv[8+l],
                                       pv[i*4+3] * kv[12+l])));
                        const float tq = fmaf(isg[i*4+l], v, qb[i*4+l]);
                        Q = fmaf(tq, v, Q);
                    }
                }
                Rm[o * RS + n] = fmaf(-0.5f, Q, LC);
            }
            __syncthreads();

            // ===== softmax over o (one thread per n); store R*a pre-multiplied =====
            if (t < N_) {
                float v[32];
                float mx = -1e30f;
#pragma unroll
                for (int oo = 0; oo < 32; ++oo) {
                    v[oo] = Rm[oo * RS + t];
                    mx = fmaxf(mx, v[oo]);
                }
                float sm = 0.f;
#pragma unroll
                for (int oo = 0; oo < 32; ++oo) {
                    v[oo] = __expf(v[oo] - mx);
                    sm += v[oo];
                }
                const float sc = A[t] / sm;
#pragma unroll
                for (int oo = 0; oo < 32; ++oo)
                    Rm[oo * RS + t] = v[oo] * sc;
            }
            __syncthreads();
        }
    }

    // ===== write outputs: poses [pix][o][16] then a_out [pix][o] =====
    if (s == 0) {
        float4* ob = (float4*)(out + (size_t)pix * 512 + o * 16);
        ob[0] = make_float4(mu[0],  mu[1],  mu[2],  mu[3]);
        ob[1] = make_float4(mu[4],  mu[5],  mu[6],  mu[7]);
        ob[2] = make_float4(mu[8],  mu[9],  mu[10], mu[11]);
        ob[3] = make_float4(mu[12], mu[13], mu[14], mu[15]);
        out[401408 + pix * 32 + o] = a_out;
    }
}

extern "C" void kernel_launch(void* const* d_in, const int* in_sizes, int n_in,
                              void* d_out, int out_size, void* d_ws, size_t ws_size,
                              hipStream_t stream)
{
    const float* poses  = (const float*)d_in[0];
    const float* acts   = (const float*)d_in[1];
    const float* kern   = (const float*)d_in[2];
    const float* beta_a = (const float*)d_in[3];
    const float* beta_u = (const float*)d_in[4];
    float* out = (float*)d_out;
    convcaps_em<<<NBLK, 256, 0, stream>>>(poses, acts, kern, beta_a, beta_u, out);
}